// Round 6
// baseline (44.839 us; speedup 1.0000x reference)
//
#include <hip/hip_runtime.h>
#include <hip/hip_bf16.h>

// Lovasz-Softmax loss, B=8, N=262144 (2^18), C=21, ignore_index=0.
// R6: HB=128 buckets, 4 LDS histogram replicas (quarter-wave split, +1-u32
// skew) to cut LDS-atomic same-address serialization; partials 5.25MB;
// K3 fused into K2 via deterministic u64 fixed-point atomics + last-block
// finish (K1 block 0 zeroes the 16B accumulator header; no memsets).

#define B_DIM 8
#define N_DIM 262144          // 2^18
#define NCLS 20               // classes 1..20
#define HB 128                // buckets
#define PX_PER_BLK 4096       // K1: 512 threads x 8 pixels
#define BLKS_PER_B 64         // 262144 / 4096
#define NBLK1 (B_DIM * BLKS_PER_B)   // 512
#define HSLOT (NCLS * HB)     // 2560 u32 per histogram (un-skewed)
#define RSTRIDE (HSLOT + 1)   // replica stride (bank skew)
#define FXSCALE 4398046511104.0  // 2^42

// ---------------------------------------------------------------------------
// Kernel 1: softmax + error bucketing -> per-block packed histograms.
// partial[blk][c-1][h] u32: lo16 = bg count, hi16 = fg count (<=4096 each).
// 4 LDS replicas split by quarter-wave (lanes 0-15/16-31/32-47/48-63).
// Block 0 also zeroes the K2 accumulator header (sumFx, cnt, done).
// ---------------------------------------------------------------------------
__global__ __launch_bounds__(512) void lovasz_hist1_kernel(
    const float* __restrict__ logits, const int* __restrict__ labels,
    unsigned* __restrict__ partials, unsigned* __restrict__ hdr) {
  __shared__ unsigned hist[4 * RSTRIDE];
  const int tid = threadIdx.x;

  if (blockIdx.x == 0 && tid < 4) hdr[tid] = 0;  // sumFx(2), cnt, done

  for (int i = tid; i < 4 * RSTRIDE; i += 512) hist[i] = 0;
  __syncthreads();

  unsigned* myh = hist + ((tid >> 4) & 3) * RSTRIDE;
  const size_t base = (size_t)blockIdx.x * PX_PER_BLK;

  #pragma unroll
  for (int j = 0; j < 8; ++j) {
    const size_t p = base + tid + j * 512;
    const int lab = labels[p];
    const float* lp = logits + p * 21;
    float ex[21];
    float denom = 0.f;
    #pragma unroll
    for (int c = 0; c < 21; ++c) {
      ex[c] = __expf(lp[c]);
      denom += ex[c];
    }
    const float inv = 1.0f / denom;
    if (lab != 0) {
      #pragma unroll
      for (int c = 1; c <= NCLS; ++c) {
        const float pc = ex[c] * inv;
        const bool fg = (lab == c);
        const float e = fg ? (1.0f - pc) : pc;     // in (0,1)
        int h = (int)(e * (float)HB);
        h = h < (HB - 1) ? h : (HB - 1);
        atomicAdd(&myh[(c - 1) * HB + h], fg ? 0x10000u : 1u);
      }
    }
  }
  __syncthreads();

  // Flush: sum 4 replicas (lo sums <= 4*4096, no carry into hi field).
  unsigned* outp = partials + (size_t)blockIdx.x * HSLOT;
  for (int i = tid; i < HSLOT; i += 512)
    outp[i] = hist[i] + hist[i + RSTRIDE] + hist[i + 2 * RSTRIDE] +
              hist[i + 3 * RSTRIDE];
}

// ---------------------------------------------------------------------------
// Kernel 2: one block (256 thr) per (b, class) row. Merge 64 block-partials
// (2-way split), descending 128-bucket scan, closed-form Lovasz term, then
// deterministic fixed-point accumulation; last block writes the scalar loss.
// Entering bucket with k fg / m bg already seen (higher-error buckets), K total:
//   fg: term += n1*e/(K+m);  k += n1;
//   bg: term += (K-k)*e*n0/((K+m)*(K+m+n0));  m += n0;
// hdr: [0..1]=sumFx u64, [2]=cnt u32, [3]=done u32 (zeroed by K1).
// ---------------------------------------------------------------------------
__global__ __launch_bounds__(256) void lovasz_scan_kernel(
    const unsigned* __restrict__ partials, unsigned* __restrict__ hdr,
    float* __restrict__ out) {
  __shared__ unsigned a1[256];
  __shared__ unsigned a0[256];
  __shared__ unsigned ts1[128];
  __shared__ unsigned ts0[128];
  __shared__ float redf[256];
  __shared__ int redi[128];

  const int tid = threadIdx.x;
  const int row = blockIdx.x;                  // b*20 + ci
  const int b = row / NCLS;
  const int ci = row % NCLS;

  // 2-way split merge: thread = (half=tid>>7, bucket=tid&127), 32 partials ea.
  const int bucket = tid & 127;
  const int half = tid >> 7;
  unsigned lo = 0, hi = 0;
  const unsigned* pp = partials +
      (size_t)(b * BLKS_PER_B + half * 32) * HSLOT + ci * HB + bucket;
  #pragma unroll 8
  for (int blk = 0; blk < 32; ++blk) {
    const unsigned v = pp[(size_t)blk * HSLOT];
    lo += v & 0xFFFFu;
    hi += v >> 16;
  }
  a1[tid] = hi; a0[tid] = lo;
  __syncthreads();

  unsigned bhi = 0, blo = 0;
  if (tid < 128) {
    bhi = a1[tid] + a1[tid + 128];
    blo = a0[tid] + a0[tid + 128];
    const int r = 127 - tid;                   // descending rank
    ts1[r] = bhi; ts0[r] = blo;
  }
  __syncthreads();

  // Inclusive Hillis-Steele scan over descending rank (128 entries).
  for (int off = 1; off < 128; off <<= 1) {
    unsigned v1 = 0, v0 = 0;
    if (tid < 128) {
      const int r = 127 - tid;
      if (r >= off) { v1 = ts1[r - off]; v0 = ts0[r - off]; }
    }
    __syncthreads();
    if (tid < 128) {
      const int r = 127 - tid;
      ts1[r] += v1; ts0[r] += v0;
    }
    __syncthreads();
  }
  const unsigned K = ts1[127];
  const unsigned V = K + ts0[127];

  float term = 0.f;
  if (tid < 128 && K > 0) {
    const int r = 127 - tid;
    unsigned k = ts1[r] - bhi;                 // fg seen before my bucket
    const unsigned m = ts0[r] - blo;           // bg seen before my bucket
    const float e = ((float)tid + 0.5f) * (1.0f / (float)HB);
    if (bhi) term += (float)bhi * e / (float)(K + m);
    k += bhi;
    if (blo) term += (float)(K - k) * e *
                     ((float)blo / ((float)(K + m) * (float)(K + m + blo)));
  }
  redf[tid] = term;
  if (tid < 128) redi[tid] = (blo | bhi) ? tid : -1;
  __syncthreads();

  for (int off = 128; off > 0; off >>= 1) {
    if (tid < off && tid + off < 256) redf[tid] += redf[tid + off];
    if (off <= 64 && tid < off)
      redi[tid] = redi[tid] > redi[tid + off] ? redi[tid] : redi[tid + off];
    __syncthreads();
  }

  if (tid == 0) {
    float t = redf[0];
    if (K == 0) {
      // Degenerate: no fg -> grad = [1,0,...] -> term = max-error midpoint.
      t = (redi[0] >= 0) ? ((float)redi[0] + 0.5f) * (1.0f / (float)HB) : 0.f;
    }
    const bool include = (V >= 2);
    unsigned long long* sumFx = (unsigned long long*)hdr;
    if (include) {
      const unsigned long long fx =
          (unsigned long long)((double)t * FXSCALE + 0.5);
      atomicAdd(sumFx, fx);
      atomicAdd(&hdr[2], 1u);                  // included rows (=20*batches)
    }
    __threadfence();
    const unsigned old = atomicAdd(&hdr[3], 1u);
    if (old == (unsigned)(B_DIM * NCLS - 1)) { // last block finishes
      const unsigned long long total = atomicAdd(sumFx, 0ULL);
      const unsigned count = atomicAdd(&hdr[2], 0u);
      const unsigned d = count > 0 ? count : 1;
      out[0] = (float)((double)total / FXSCALE / (double)d);
    }
  }
}

extern "C" void kernel_launch(void* const* d_in, const int* in_sizes, int n_in,
                              void* d_out, int out_size, void* d_ws, size_t ws_size,
                              hipStream_t stream) {
  const float* logits = (const float*)d_in[0];
  const int* labels = (const int*)d_in[1];
  float* out = (float*)d_out;

  char* ws = (char*)d_ws;
  unsigned* hdr = (unsigned*)ws;                     // 4 u32 @ 0 (K1-zeroed)
  unsigned* partials = (unsigned*)(ws + 1024);       // 512 * 2560 u32 = 5.25 MB

  lovasz_hist1_kernel<<<NBLK1, 512, 0, stream>>>(logits, labels, partials, hdr);
  lovasz_scan_kernel<<<B_DIM * NCLS, 256, 0, stream>>>(partials, hdr, out);
}